// Round 4
// baseline (322.129 us; speedup 1.0000x reference)
//
#include <hip/hip_runtime.h>
#include <cstdint>
#include <cstddef>

typedef _Float16 f16;
typedef f16 f16x4 __attribute__((ext_vector_type(4)));
typedef f16 f16x8 __attribute__((ext_vector_type(8)));
typedef float f32x4 __attribute__((ext_vector_type(4)));

#define NB    64      // batch
#define NPOMO 200
#define NNODE 201
#define NEMB  512
#define NH    16
#define ND    32

__device__ __forceinline__ void gload16(const void* g, void* l) {
  __builtin_amdgcn_global_load_lds((const __attribute__((address_space(1))) void*)g,
                                   (__attribute__((address_space(3))) void*)l, 16, 0, 0);
}

// ---------------- fused prep: casts + weight transposes in ONE dispatch ----------------
// blocks [0,6432): cast encoded_nodes -> Xnh (fp16)
// blocks [6432,19232): build Qcat (12800x1024)
// blocks [19232,24352): build WkvT / WqT / WcT

__global__ void prep_kernel(const float* __restrict__ enc, const float* __restrict__ q1,
                            const float* __restrict__ ql, const float* __restrict__ Wk,
                            const float* __restrict__ Wv, const float* __restrict__ Wqf,
                            const float* __restrict__ Wql, const float* __restrict__ Wc,
                            f16* __restrict__ Xnh, f16* __restrict__ Qcat,
                            f16* __restrict__ wkvT, f16* __restrict__ wqT,
                            f16* __restrict__ wcT) {
  const int bx = blockIdx.x;
  const int tid = threadIdx.x;
  if (bx < 6432) {
    int i = bx * 256 + tid;
    if (i < 1646592) {
      float4 v = ((const float4*)enc)[i];
      f16x4 h = {(f16)v.x, (f16)v.y, (f16)v.z, (f16)v.w};
      ((f16x4*)Xnh)[i] = h;
    }
  } else if (bx < 19232) {
    int i = (bx - 6432) * 256 + tid;   // 12800*256 groups of 4
    int row = i >> 8;
    int g = i & 255;
    const float* src = (g < 128) ? (q1 + (size_t)row * 512 + g * 4)
                                 : (ql + (size_t)row * 512 + (g - 128) * 4);
    float4 v = *(const float4*)src;
    f16x4 h = {(f16)v.x, (f16)v.y, (f16)v.z, (f16)v.w};
    ((f16x4*)Qcat)[i] = h;
  } else {
    int i = (bx - 19232) * 256 + tid;
    if (i < 524288) {                       // WkvT (1024x512)
      int j = i >> 9, k = i & 511;
      float v = (j < 512) ? Wk[(size_t)k * 512 + j] : Wv[(size_t)k * 512 + (j - 512)];
      wkvT[i] = (f16)v;
    } else if (i < 1048576) {               // WqcatT (512x1024)
      int t = i - 524288;
      int j = t >> 10, k = t & 1023;
      float v = (k < 512) ? Wqf[(size_t)k * 512 + j] : Wql[(size_t)(k - 512) * 512 + j];
      wqT[t] = (f16)v;
    } else if (i < 1310720) {               // WcT (512x512)
      int t = i - 1048576;
      int j = t >> 9, k = t & 511;
      wcT[t] = (f16)Wc[(size_t)k * 512 + j];
    }
  }
}

// ---------------- GEMM body: C(MxN) = A(MxK) * B(NxK)^T (+bias), fp16 out ----------------
// 128x128 tile, BK=64, 256 threads, global_load_lds staging, XOR-swizzled 16B chunks.

__device__ __forceinline__ void gemm_body(
    const f16* __restrict__ A, const f16* __restrict__ B, f16* __restrict__ C,
    const float* __restrict__ bias, int M, int N, int K, int m0, int n0,
    f16* As, f16* Bs) {
  const int tid = threadIdx.x;
  const int wave = tid >> 6, lane = tid & 63;
  const int qd = lane >> 4, c = lane & 15;
  const int wm = wave >> 1, wn = wave & 1;
  const int srow = lane >> 3, sj = lane & 7;

  f32x4 acc[4][4];
#pragma unroll
  for (int i = 0; i < 4; ++i)
#pragma unroll
    for (int j = 0; j < 4; ++j) acc[i][j] = (f32x4){0.f, 0.f, 0.f, 0.f};

  for (int kc = 0; kc < K; kc += 64) {
#pragma unroll
    for (int i = 0; i < 4; ++i) {
      int row = wave * 32 + i * 8 + srow;
      int gr = m0 + row; if (gr >= M) gr = M - 1;
      int gj = sj ^ (row & 7);
      gload16(A + (size_t)gr * K + kc + gj * 8, As + row * 64 + sj * 8);
    }
#pragma unroll
    for (int i = 0; i < 4; ++i) {
      int row = wave * 32 + i * 8 + srow;
      int gj = sj ^ (row & 7);
      gload16(B + (size_t)(n0 + row) * K + kc + gj * 8, Bs + row * 64 + sj * 8);
    }
    __syncthreads();
#pragma unroll
    for (int kk = 0; kk < 2; ++kk) {
      f16x8 af[4], bf[4];
#pragma unroll
      for (int t = 0; t < 4; ++t) {
        int ra = wm * 64 + t * 16 + c;
        af[t] = *(const f16x8*)(As + ra * 64 + (((kk * 4 + qd) ^ (ra & 7)) * 8));
        int rb = wn * 64 + t * 16 + c;
        bf[t] = *(const f16x8*)(Bs + rb * 64 + (((kk * 4 + qd) ^ (rb & 7)) * 8));
      }
#pragma unroll
      for (int mt = 0; mt < 4; ++mt)
#pragma unroll
        for (int nt = 0; nt < 4; ++nt)
          acc[mt][nt] = __builtin_amdgcn_mfma_f32_16x16x32_f16(af[mt], bf[nt], acc[mt][nt], 0, 0, 0);
    }
    __syncthreads();
  }

#pragma unroll
  for (int mt = 0; mt < 4; ++mt) {
#pragma unroll
    for (int nt = 0; nt < 4; ++nt) {
      int col = n0 + wn * 64 + nt * 16 + c;
      float bv = bias ? bias[col] : 0.0f;
#pragma unroll
      for (int r = 0; r < 4; ++r) {
        int row = m0 + wm * 64 + mt * 16 + qd * 4 + r;
        if (row < M) C[(size_t)row * N + col] = (f16)(acc[mt][nt][r] + bv);
      }
    }
  }
}

// fused projections: blocks [0,808) = KV-proj (101x8), [808,1208) = Q-proj (100x4)
__global__ __launch_bounds__(256, 2) void gemm_proj(
    const f16* __restrict__ Xnh, const f16* __restrict__ WkvT, f16* __restrict__ KVp,
    const f16* __restrict__ Qcat, const f16* __restrict__ WqT, f16* __restrict__ Qp) {
  __shared__ f16 As[128 * 64];
  __shared__ f16 Bs[128 * 64];
  const int bx = blockIdx.x;
  if (bx < 808) {
    gemm_body(Xnh, WkvT, KVp, nullptr, 12864, 1024, 512, (bx % 101) * 128, (bx / 101) * 128, As, Bs);
  } else {
    int t = bx - 808;
    gemm_body(Qcat, WqT, Qp, nullptr, 12800, 512, 1024, (t % 100) * 128, (t / 100) * 128, As, Bs);
  }
}

__global__ __launch_bounds__(256, 2) void gemm_wc(
    const f16* __restrict__ Oc, const f16* __restrict__ WcT, f16* __restrict__ mhb,
    const float* __restrict__ bc) {
  __shared__ f16 As[128 * 64];
  __shared__ f16 Bs[128 * 64];
  const int bx = blockIdx.x;
  gemm_body(Oc, WcT, mhb, bc, 12800, 512, 512, (bx % 100) * 128, (bx / 100) * 128, As, Bs);
}

// ---------------- fused multi-head attention (S^T formulation) ----------------
// bid = h*256 + (b*4+qq): all 16 heads sharing a mask slice map to the same bid%8
// (same XCD) so the head-independent mask stays L2-resident (~1.3 MB/XCD working set).

#define VSTR 268

__global__ __launch_bounds__(256, 6) void attn_kernel(
    const f16* __restrict__ Qp, const f16* __restrict__ KV,
    const float* __restrict__ mask, f16* __restrict__ Oc) {
  __shared__ f16 Vt[32 * VSTR];           // V^T[d][node], 17152 B
  const int bid = blockIdx.x;
  const int b4q = bid & 255;
  const int h = bid >> 8;
  const int b = b4q >> 2;
  const int qq = b4q & 3;
  const int tid = threadIdx.x;
  const int wave = tid >> 6, lane = tid & 63;
  const int qd = lane >> 4, c = lane & 15;

  for (int idx = tid; idx < 208 * 8; idx += 256) {
    int m = idx >> 3, ch = idx & 7;
    f16x4 v = (f16x4){0, 0, 0, 0};
    if (m < 201) v = *(const f16x4*)(KV + ((size_t)(b * NNODE + m)) * 1024 + 512 + h * 32 + ch * 4);
    Vt[(ch * 4 + 0) * VSTR + m] = v.x;
    Vt[(ch * 4 + 1) * VSTR + m] = v.y;
    Vt[(ch * 4 + 2) * VSTR + m] = v.z;
    Vt[(ch * 4 + 3) * VSTR + m] = v.w;
  }
  __syncthreads();

  const int start = (qq == 0) ? 0 : (1 + 3 * qq);     // {0,4,7,10}
  const int ntile = (qq == 0) ? 4 : 3;
  const int rt = start + wave;
  if (wave >= ntile) return;

  const int r0 = rt * 16;
  const int qrow = min(r0 + c, 199);
  const float scale = 0.17677669529663687f;           // 1/sqrt(32)

  f16x8 aq = *(const f16x8*)(Qp + ((size_t)(b * NPOMO + qrow)) * 512 + h * 32 + qd * 8);

  f32x4 s[13];
#pragma unroll
  for (int nt = 0; nt < 13; ++nt) {
    int node = nt * 16 + c; if (node > 200) node = 200;
    f16x8 ak = *(const f16x8*)(KV + ((size_t)(b * NNODE + node)) * 1024 + h * 32 + qd * 8);
    f32x4 z = (f32x4){0.f, 0.f, 0.f, 0.f};
    s[nt] = __builtin_amdgcn_mfma_f32_16x16x32_f16(ak, aq, z, 0, 0, 0);
  }

  float mx = -3e38f;
#pragma unroll
  for (int nt = 0; nt < 13; ++nt) {
    const int col0 = nt * 16 + qd * 4;
    float4 mv = make_float4(0.f, 0.f, 0.f, 0.f);
    if (col0 < 200)
      mv = *(const float4*)(mask + ((size_t)b * NPOMO + qrow) * 200 + col0);
#pragma unroll
    for (int r = 0; r < 4; ++r) {
      int node = col0 + r;
      float v;
      if (node > 200)      v = -3e38f;
      else if (node == 200) v = s[nt][r] * scale;
      else                  v = s[nt][r] * scale + ((const float*)&mv)[r];
      s[nt][r] = v;
      mx = fmaxf(mx, v);
    }
  }
  mx = fmaxf(mx, __shfl_xor(mx, 16));
  mx = fmaxf(mx, __shfl_xor(mx, 32));

  float sm = 0.f;
  f16x4 pf[13];
#pragma unroll
  for (int nt = 0; nt < 13; ++nt) {
    f16x4 p4;
#pragma unroll
    for (int r = 0; r < 4; ++r) {
      float p = __expf(s[nt][r] - mx);
      sm += p;
      p4[r] = (f16)p;
    }
    pf[nt] = p4;
  }
  sm += __shfl_xor(sm, 16);
  sm += __shfl_xor(sm, 32);
  const float inv = 1.0f / sm;

  f32x4 o0 = (f32x4){0.f, 0.f, 0.f, 0.f};
  f32x4 o1 = (f32x4){0.f, 0.f, 0.f, 0.f};
#pragma unroll
  for (int nt = 0; nt < 13; ++nt) {
    const int nb = nt * 16 + qd * 4;
    f16x4 av0 = *(const f16x4*)(Vt + c * VSTR + nb);
    f16x4 av1 = *(const f16x4*)(Vt + (c + 16) * VSTR + nb);
    o0 = __builtin_amdgcn_mfma_f32_16x16x16f16(av0, pf[nt], o0, 0, 0, 0);
    o1 = __builtin_amdgcn_mfma_f32_16x16x16f16(av1, pf[nt], o1, 0, 0, 0);
  }

  const int row = r0 + c;
  if (row < 200) {
    f16* dst = Oc + ((size_t)(b * NPOMO + row)) * 512 + h * 32 + qd * 4;
    f16x4 w0 = {(f16)(o0[0] * inv), (f16)(o0[1] * inv), (f16)(o0[2] * inv), (f16)(o0[3] * inv)};
    f16x4 w1 = {(f16)(o1[0] * inv), (f16)(o1[1] * inv), (f16)(o1[2] * inv), (f16)(o1[3] * inv)};
    *(f16x4*)dst = w0;
    *(f16x4*)(dst + 16) = w1;
  }
}

// ---------------- final: score2^T -> 10*tanh + mask -> softmax (no-LDS GEMM) ----------------

__global__ __launch_bounds__(256, 4) void final_kernel(
    const f16* __restrict__ mh, const f16* __restrict__ Xnh,
    const float* __restrict__ mask, float* __restrict__ out) {
  __shared__ float xmax[4][16];
  __shared__ float xsum[4][16];
  const int b = blockIdx.x / 13;
  const int tile = blockIdx.x % 13;
  const int r0 = tile * 16;
  const int tid = threadIdx.x;
  const int wave = tid >> 6, lane = tid & 63;
  const int qd = lane >> 4, c = lane & 15;

  const int nt0 = (wave == 0) ? 0 : (3 * wave + 1);   // {0,4,7,10}
  const int cnt = (wave == 0) ? 4 : 3;

  const int qrow = min(r0 + c, 199);
  const size_t rbase = ((size_t)(b * NPOMO + qrow)) * 512;

  size_t abase[4];
#pragma unroll
  for (int i = 0; i < 4; ++i) {
    int nt = nt0 + i;
    int nd = nt * 16 + c; if (nd > 200) nd = 200;
    abase[i] = ((size_t)(b * NNODE + nd)) * 512;
  }

  f32x4 acc[4];
#pragma unroll
  for (int i = 0; i < 4; ++i) acc[i] = (f32x4){0.f, 0.f, 0.f, 0.f};

#pragma unroll 4
  for (int kc = 0; kc < 512; kc += 32) {
    f16x8 bq = *(const f16x8*)(mh + rbase + kc + qd * 8);
#pragma unroll
    for (int i = 0; i < 4; ++i) {
      if (i < cnt) {
        f16x8 a = *(const f16x8*)(Xnh + abase[i] + kc + qd * 8);
        acc[i] = __builtin_amdgcn_mfma_f32_16x16x32_f16(a, bq, acc[i], 0, 0, 0);
      }
    }
  }

  const float invS = 1.0f / 22.627416997969522f;
  float mx = -3e38f;
#pragma unroll
  for (int i = 0; i < 4; ++i) {
    if (i >= cnt) break;
    const int nt = nt0 + i;
    const int col0 = nt * 16 + qd * 4;
    float4 mv = make_float4(0.f, 0.f, 0.f, 0.f);
    if (col0 < 200)
      mv = *(const float4*)(mask + ((size_t)b * NPOMO + qrow) * 200 + col0);
#pragma unroll
    for (int r = 0; r < 4; ++r) {
      int node = col0 + r;
      float v;
      if (node < 200) {
        float t = __expf(2.0f * acc[i][r] * invS);
        float th = 1.0f - 2.0f / (t + 1.0f);
        v = 10.0f * th + ((const float*)&mv)[r];
      } else {
        v = -3e38f;
      }
      acc[i][r] = v;
      mx = fmaxf(mx, v);
    }
  }
  mx = fmaxf(mx, __shfl_xor(mx, 16));
  mx = fmaxf(mx, __shfl_xor(mx, 32));
  if (lane < 16) xmax[wave][lane] = mx;
  __syncthreads();
  mx = fmaxf(fmaxf(xmax[0][c], xmax[1][c]), fmaxf(xmax[2][c], xmax[3][c]));

  float sm = 0.f;
#pragma unroll
  for (int i = 0; i < 4; ++i) {
    if (i >= cnt) break;
#pragma unroll
    for (int r = 0; r < 4; ++r) {
      float p = __expf(acc[i][r] - mx);
      acc[i][r] = p;
      sm += p;
    }
  }
  sm += __shfl_xor(sm, 16);
  sm += __shfl_xor(sm, 32);
  if (lane < 16) xsum[wave][lane] = sm;
  __syncthreads();
  const float tot = xsum[0][c] + xsum[1][c] + xsum[2][c] + xsum[3][c];
  const float inv = 1.0f / tot;

  const int row = r0 + c;
  if (row < 200) {
#pragma unroll
    for (int i = 0; i < 4; ++i) {
      if (i >= cnt) break;
      const int col0 = (nt0 + i) * 16 + qd * 4;
      if (col0 < 200) {
        float4 o;
        o.x = acc[i][0] * inv; o.y = acc[i][1] * inv;
        o.z = acc[i][2] * inv; o.w = acc[i][3] * inv;
        *(float4*)(out + ((size_t)b * NPOMO + row) * 200 + col0) = o;
      }
    }
  }
}

// ---------------- launcher ----------------

extern "C" void kernel_launch(void* const* d_in, const int* in_sizes, int n_in,
                              void* d_out, int out_size, void* d_ws, size_t ws_size,
                              hipStream_t stream) {
  (void)in_sizes; (void)n_in; (void)out_size; (void)ws_size;
  const float* enc   = (const float*)d_in[0];
  const float* q1    = (const float*)d_in[1];
  const float* qlast = (const float*)d_in[2];
  const float* mask  = (const float*)d_in[3];
  const float* Wqf   = (const float*)d_in[4];
  const float* Wql   = (const float*)d_in[5];
  const float* Wk    = (const float*)d_in[6];
  const float* Wv    = (const float*)d_in[7];
  const float* Wc    = (const float*)d_in[8];
  const float* bc    = (const float*)d_in[9];
  float* out = (float*)d_out;

  char* ws = (char*)d_ws;
  f16* Xnh  = (f16*)(ws + 0);           // 12864*512*2  = 13,172,736
  f16* Qcat = (f16*)(ws + 13172736);    // 12800*1024*2 = 26,214,400
  f16* WkvT = (f16*)(ws + 39387136);    // 1024*512*2   =  1,048,576
  f16* WqT  = (f16*)(ws + 40435712);    // 512*1024*2   =  1,048,576
  f16* WcT  = (f16*)(ws + 41484288);    // 512*512*2    =    524,288
  f16* KVp  = (f16*)(ws + 42008576);    // 12864*1024*2 = 26,345,472
  f16* Qp   = (f16*)(ws + 68354048);    // 12800*512*2  = 13,107,200
  f16* Oc   = (f16*)(ws + 81461248);    // 12800*512*2  = 13,107,200
  f16* mhb  = (f16*)(ws + 94568448);    // 12800*512*2  = 13,107,200  (end 107,675,648)

  hipLaunchKernelGGL(prep_kernel, dim3(24352), dim3(256), 0, stream,
                     enc, q1, qlast, Wk, Wv, Wqf, Wql, Wc, Xnh, Qcat, WkvT, WqT, WcT);
  hipLaunchKernelGGL(gemm_proj, dim3(1208), dim3(256), 0, stream,
                     Xnh, WkvT, KVp, Qcat, WqT, Qp);
  hipLaunchKernelGGL(attn_kernel, dim3(4096), dim3(256), 0, stream, Qp, KVp, mask, Oc);
  hipLaunchKernelGGL(gemm_wc, dim3(400), dim3(256), 0, stream, Oc, WcT, mhb, bc);
  hipLaunchKernelGGL(final_kernel, dim3(832), dim3(256), 0, stream, mhb, Xnh, mask, out);
}

// Round 5
// 296.173 us; speedup vs baseline: 1.0876x; 1.0876x over previous
//
#include <hip/hip_runtime.h>
#include <cstdint>
#include <cstddef>

typedef _Float16 f16;
typedef f16 f16x4 __attribute__((ext_vector_type(4)));
typedef f16 f16x8 __attribute__((ext_vector_type(8)));
typedef float f32x4 __attribute__((ext_vector_type(4)));

#define NB    64      // batch
#define NPOMO 200
#define NNODE 201
#define NEMB  512
#define NH    16
#define ND    32
#define VTSTR 208     // node-dim stride of VT

__device__ __forceinline__ void gload16(const void* g, void* l) {
  __builtin_amdgcn_global_load_lds((const __attribute__((address_space(1))) void*)g,
                                   (__attribute__((address_space(3))) void*)l, 16, 0, 0);
}

// ---------------- fused prep: casts + weight transposes in ONE dispatch ----------------

__global__ void prep_kernel(const float* __restrict__ enc, const float* __restrict__ q1,
                            const float* __restrict__ ql, const float* __restrict__ Wk,
                            const float* __restrict__ Wv, const float* __restrict__ Wqf,
                            const float* __restrict__ Wql, const float* __restrict__ Wc,
                            f16* __restrict__ Xnh, f16* __restrict__ Qcat,
                            f16* __restrict__ wkvT, f16* __restrict__ wqT,
                            f16* __restrict__ wcT) {
  const int bx = blockIdx.x;
  const int tid = threadIdx.x;
  if (bx < 6432) {
    int i = bx * 256 + tid;
    if (i < 1646592) {
      float4 v = ((const float4*)enc)[i];
      f16x4 h = {(f16)v.x, (f16)v.y, (f16)v.z, (f16)v.w};
      ((f16x4*)Xnh)[i] = h;
    }
  } else if (bx < 19232) {
    int i = (bx - 6432) * 256 + tid;   // 12800*256 groups of 4
    int row = i >> 8;
    int g = i & 255;
    const float* src = (g < 128) ? (q1 + (size_t)row * 512 + g * 4)
                                 : (ql + (size_t)row * 512 + (g - 128) * 4);
    float4 v = *(const float4*)src;
    f16x4 h = {(f16)v.x, (f16)v.y, (f16)v.z, (f16)v.w};
    ((f16x4*)Qcat)[i] = h;
  } else {
    int i = (bx - 19232) * 256 + tid;
    if (i < 524288) {                       // WkvT (1024x512)
      int j = i >> 9, k = i & 511;
      float v = (j < 512) ? Wk[(size_t)k * 512 + j] : Wv[(size_t)k * 512 + (j - 512)];
      wkvT[i] = (f16)v;
    } else if (i < 1048576) {               // WqcatT (512x1024)
      int t = i - 524288;
      int j = t >> 10, k = t & 1023;
      float v = (k < 512) ? Wqf[(size_t)k * 512 + j] : Wql[(size_t)(k - 512) * 512 + j];
      wqT[t] = (f16)v;
    } else if (i < 1310720) {               // WcT (512x512)
      int t = i - 1048576;
      int j = t >> 9, k = t & 511;
      wcT[t] = (f16)Wc[(size_t)k * 512 + j];
    }
  }
}

// ---------------- GEMM body: C(MxN) = A(MxK) * B(NxK)^T (+bias), fp16 out ----------------
// 128x128 tile, BK=64, 256 threads, global_load_lds staging, XOR-swizzled 16B chunks.
// If vtp != nullptr (KV mode): cols <512 -> Kp[row*512+col]; cols >=512 -> transposed
// store VT[b][h][d][node] (C-layout lane holds 4 consecutive nodes at fixed d).

__device__ __forceinline__ void gemm_body(
    const f16* __restrict__ A, const f16* __restrict__ B, f16* __restrict__ C,
    const float* __restrict__ bias, int M, int N, int K, int m0, int n0,
    f16* As, f16* Bs, f16* __restrict__ vtp) {
  const int tid = threadIdx.x;
  const int wave = tid >> 6, lane = tid & 63;
  const int qd = lane >> 4, c = lane & 15;
  const int wm = wave >> 1, wn = wave & 1;
  const int srow = lane >> 3, sj = lane & 7;

  f32x4 acc[4][4];
#pragma unroll
  for (int i = 0; i < 4; ++i)
#pragma unroll
    for (int j = 0; j < 4; ++j) acc[i][j] = (f32x4){0.f, 0.f, 0.f, 0.f};

  for (int kc = 0; kc < K; kc += 64) {
#pragma unroll
    for (int i = 0; i < 4; ++i) {
      int row = wave * 32 + i * 8 + srow;
      int gr = m0 + row; if (gr >= M) gr = M - 1;
      int gj = sj ^ (row & 7);
      gload16(A + (size_t)gr * K + kc + gj * 8, As + row * 64 + sj * 8);
    }
#pragma unroll
    for (int i = 0; i < 4; ++i) {
      int row = wave * 32 + i * 8 + srow;
      int gj = sj ^ (row & 7);
      gload16(B + (size_t)(n0 + row) * K + kc + gj * 8, Bs + row * 64 + sj * 8);
    }
    __syncthreads();
#pragma unroll
    for (int kk = 0; kk < 2; ++kk) {
      f16x8 af[4], bf[4];
#pragma unroll
      for (int t = 0; t < 4; ++t) {
        int ra = wm * 64 + t * 16 + c;
        af[t] = *(const f16x8*)(As + ra * 64 + (((kk * 4 + qd) ^ (ra & 7)) * 8));
        int rb = wn * 64 + t * 16 + c;
        bf[t] = *(const f16x8*)(Bs + rb * 64 + (((kk * 4 + qd) ^ (rb & 7)) * 8));
      }
#pragma unroll
      for (int mt = 0; mt < 4; ++mt)
#pragma unroll
        for (int nt = 0; nt < 4; ++nt)
          acc[mt][nt] = __builtin_amdgcn_mfma_f32_16x16x32_f16(af[mt], bf[nt], acc[mt][nt], 0, 0, 0);
    }
    __syncthreads();
  }

#pragma unroll
  for (int mt = 0; mt < 4; ++mt) {
#pragma unroll
    for (int nt = 0; nt < 4; ++nt) {
      int col = n0 + wn * 64 + nt * 16 + c;
      float bv = bias ? bias[col] : 0.0f;
#pragma unroll
      for (int r = 0; r < 4; ++r) {
        int row = m0 + wm * 64 + mt * 16 + qd * 4 + r;
        if (row < M) {
          f16 hv = (f16)(acc[mt][nt][r] + bv);
          if (!vtp) {
            C[(size_t)row * N + col] = hv;
          } else if (col < 512) {
            C[(size_t)row * 512 + col] = hv;            // Kp
          } else {
            int bb = row / 201, node = row - bb * 201;  // magic-mul div
            int hd = col - 512;
            vtp[(((size_t)(bb * NH) + (hd >> 5)) * 32 + (hd & 31)) * VTSTR + node] = hv;
          }
        }
      }
    }
  }
}

// fused projections: blocks [0,808) = KV-proj (101x8), [808,1208) = Q-proj (100x4)
__global__ __launch_bounds__(256, 2) void gemm_proj(
    const f16* __restrict__ Xnh, const f16* __restrict__ WkvT, f16* __restrict__ Kp,
    f16* __restrict__ VT, const f16* __restrict__ Qcat, const f16* __restrict__ WqT,
    f16* __restrict__ Qp) {
  __shared__ f16 As[128 * 64];
  __shared__ f16 Bs[128 * 64];
  const int bx = blockIdx.x;
  if (bx < 808) {
    gemm_body(Xnh, WkvT, Kp, nullptr, 12864, 1024, 512, (bx % 101) * 128, (bx / 101) * 128, As, Bs, VT);
  } else {
    int t = bx - 808;
    gemm_body(Qcat, WqT, Qp, nullptr, 12800, 512, 1024, (t % 100) * 128, (t / 100) * 128, As, Bs, nullptr);
  }
}

__global__ __launch_bounds__(256, 2) void gemm_wc(
    const f16* __restrict__ Oc, const f16* __restrict__ WcT, f16* __restrict__ mhb,
    const float* __restrict__ bc) {
  __shared__ f16 As[128 * 64];
  __shared__ f16 Bs[128 * 64];
  const int bx = blockIdx.x;
  gemm_body(Oc, WcT, mhb, bc, 12800, 512, 512, (bx % 100) * 128, (bx / 100) * 128, As, Bs, nullptr);
}

// ---------------- fused multi-head attention (S^T, zero-LDS) ----------------
// grid = 64 b x 13 rt x 4 head-groups; wave w of a block handles head hg*4+w on the
// SAME 16 q-rows -> mask rows shared via L1 across waves; b-major bids keep Kp/VT/mask
// slices L2-resident. PV A-fragments load straight from global VT (contiguous f16x4).

__global__ __launch_bounds__(256, 4) void attn_kernel(
    const f16* __restrict__ Qp, const f16* __restrict__ Kp,
    const f16* __restrict__ VT, const float* __restrict__ mask,
    f16* __restrict__ Oc) {
  const int bid = blockIdx.x;
  const int hg = bid & 3;
  const int rt = (bid >> 2) % 13;
  const int b = bid / 52;
  const int wave = threadIdx.x >> 6, lane = threadIdx.x & 63;
  const int qd = lane >> 4, c = lane & 15;
  const int h = hg * 4 + wave;

  const int r0 = rt * 16;
  const int qrow = min(r0 + c, 199);
  const float scale = 0.17677669529663687f;           // 1/sqrt(32)

  f16x8 aq = *(const f16x8*)(Qp + ((size_t)(b * NPOMO + qrow)) * 512 + h * 32 + qd * 8);

  f32x4 s[13];
#pragma unroll
  for (int nt = 0; nt < 13; ++nt) {
    int node = nt * 16 + c; if (node > 200) node = 200;
    f16x8 ak = *(const f16x8*)(Kp + ((size_t)(b * NNODE + node)) * 512 + h * 32 + qd * 8);
    f32x4 z = (f32x4){0.f, 0.f, 0.f, 0.f};
    s[nt] = __builtin_amdgcn_mfma_f32_16x16x32_f16(ak, aq, z, 0, 0, 0);
  }

  float mx = -3e38f;
#pragma unroll
  for (int nt = 0; nt < 13; ++nt) {
    const int col0 = nt * 16 + qd * 4;
    float4 mv = make_float4(0.f, 0.f, 0.f, 0.f);
    if (col0 < 200)
      mv = *(const float4*)(mask + ((size_t)b * NPOMO + qrow) * 200 + col0);
#pragma unroll
    for (int r = 0; r < 4; ++r) {
      int node = col0 + r;
      float v;
      if (node > 200)      v = -3e38f;
      else if (node == 200) v = s[nt][r] * scale;
      else                  v = s[nt][r] * scale + ((const float*)&mv)[r];
      s[nt][r] = v;
      mx = fmaxf(mx, v);
    }
  }
  mx = fmaxf(mx, __shfl_xor(mx, 16));
  mx = fmaxf(mx, __shfl_xor(mx, 32));

  float sm = 0.f;
  f16x4 pf[13];
#pragma unroll
  for (int nt = 0; nt < 13; ++nt) {
    f16x4 p4;
#pragma unroll
    for (int r = 0; r < 4; ++r) {
      float p = __expf(s[nt][r] - mx);
      sm += p;
      p4[r] = (f16)p;
    }
    pf[nt] = p4;
  }
  sm += __shfl_xor(sm, 16);
  sm += __shfl_xor(sm, 32);
  const float inv = 1.0f / sm;

  // O^T = V^T · P^T, A-fragments straight from global VT
  const f16* vbase = VT + ((size_t)(b * NH + h)) * 32 * VTSTR;
  f32x4 o0 = (f32x4){0.f, 0.f, 0.f, 0.f};
  f32x4 o1 = (f32x4){0.f, 0.f, 0.f, 0.f};
#pragma unroll
  for (int nt = 0; nt < 13; ++nt) {
    const int nb = nt * 16 + qd * 4;
    f16x4 av0 = *(const f16x4*)(vbase + c * VTSTR + nb);
    f16x4 av1 = *(const f16x4*)(vbase + (c + 16) * VTSTR + nb);
    o0 = __builtin_amdgcn_mfma_f32_16x16x16f16(av0, pf[nt], o0, 0, 0, 0);
    o1 = __builtin_amdgcn_mfma_f32_16x16x16f16(av1, pf[nt], o1, 0, 0, 0);
  }

  const int row = r0 + c;
  if (row < 200) {
    f16* dst = Oc + ((size_t)(b * NPOMO + row)) * 512 + h * 32 + qd * 4;
    f16x4 w0 = {(f16)(o0[0] * inv), (f16)(o0[1] * inv), (f16)(o0[2] * inv), (f16)(o0[3] * inv)};
    f16x4 w1 = {(f16)(o1[0] * inv), (f16)(o1[1] * inv), (f16)(o1[2] * inv), (f16)(o1[3] * inv)};
    *(f16x4*)dst = w0;
    *(f16x4*)(dst + 16) = w1;
  }
}

// ---------------- final: score2^T -> 10*tanh + mask -> softmax (no-LDS GEMM) ----------------

__global__ __launch_bounds__(256, 4) void final_kernel(
    const f16* __restrict__ mh, const f16* __restrict__ Xnh,
    const float* __restrict__ mask, float* __restrict__ out) {
  __shared__ float xmax[4][16];
  __shared__ float xsum[4][16];
  const int b = blockIdx.x / 13;
  const int tile = blockIdx.x % 13;
  const int r0 = tile * 16;
  const int tid = threadIdx.x;
  const int wave = tid >> 6, lane = tid & 63;
  const int qd = lane >> 4, c = lane & 15;

  const int nt0 = (wave == 0) ? 0 : (3 * wave + 1);   // {0,4,7,10}
  const int cnt = (wave == 0) ? 4 : 3;

  const int qrow = min(r0 + c, 199);
  const size_t rbase = ((size_t)(b * NPOMO + qrow)) * 512;

  size_t abase[4];
#pragma unroll
  for (int i = 0; i < 4; ++i) {
    int nt = nt0 + i;
    int nd = nt * 16 + c; if (nd > 200) nd = 200;
    abase[i] = ((size_t)(b * NNODE + nd)) * 512;
  }

  f32x4 acc[4];
#pragma unroll
  for (int i = 0; i < 4; ++i) acc[i] = (f32x4){0.f, 0.f, 0.f, 0.f};

#pragma unroll 4
  for (int kc = 0; kc < 512; kc += 32) {
    f16x8 bq = *(const f16x8*)(mh + rbase + kc + qd * 8);
#pragma unroll
    for (int i = 0; i < 4; ++i) {
      if (i < cnt) {
        f16x8 a = *(const f16x8*)(Xnh + abase[i] + kc + qd * 8);
        acc[i] = __builtin_amdgcn_mfma_f32_16x16x32_f16(a, bq, acc[i], 0, 0, 0);
      }
    }
  }

  const float invS = 1.0f / 22.627416997969522f;
  float mx = -3e38f;
#pragma unroll
  for (int i = 0; i < 4; ++i) {
    if (i >= cnt) break;
    const int nt = nt0 + i;
    const int col0 = nt * 16 + qd * 4;
    float4 mv = make_float4(0.f, 0.f, 0.f, 0.f);
    if (col0 < 200)
      mv = *(const float4*)(mask + ((size_t)b * NPOMO + qrow) * 200 + col0);
#pragma unroll
    for (int r = 0; r < 4; ++r) {
      int node = col0 + r;
      float v;
      if (node < 200) {
        float t = __expf(2.0f * acc[i][r] * invS);
        float th = 1.0f - 2.0f / (t + 1.0f);
        v = 10.0f * th + ((const float*)&mv)[r];
      } else {
        v = -3e38f;
      }
      acc[i][r] = v;
      mx = fmaxf(mx, v);
    }
  }
  mx = fmaxf(mx, __shfl_xor(mx, 16));
  mx = fmaxf(mx, __shfl_xor(mx, 32));
  if (lane < 16) xmax[wave][lane] = mx;
  __syncthreads();
  mx = fmaxf(fmaxf(xmax[0][c], xmax[1][c]), fmaxf(xmax[2][c], xmax[3][c]));

  float sm = 0.f;
#pragma unroll
  for (int i = 0; i < 4; ++i) {
    if (i >= cnt) break;
#pragma unroll
    for (int r = 0; r < 4; ++r) {
      float p = __expf(acc[i][r] - mx);
      acc[i][r] = p;
      sm += p;
    }
  }
  sm += __shfl_xor(sm, 16);
  sm += __shfl_xor(sm, 32);
  if (lane < 16) xsum[wave][lane] = sm;
  __syncthreads();
  const float tot = xsum[0][c] + xsum[1][c] + xsum[2][c] + xsum[3][c];
  const float inv = 1.0f / tot;

  const int row = r0 + c;
  if (row < 200) {
#pragma unroll
    for (int i = 0; i < 4; ++i) {
      if (i >= cnt) break;
      const int col0 = (nt0 + i) * 16 + qd * 4;
      if (col0 < 200) {
        float4 o;
        o.x = acc[i][0] * inv; o.y = acc[i][1] * inv;
        o.z = acc[i][2] * inv; o.w = acc[i][3] * inv;
        *(float4*)(out + ((size_t)b * NPOMO + row) * 200 + col0) = o;
      }
    }
  }
}

// ---------------- launcher ----------------

extern "C" void kernel_launch(void* const* d_in, const int* in_sizes, int n_in,
                              void* d_out, int out_size, void* d_ws, size_t ws_size,
                              hipStream_t stream) {
  (void)in_sizes; (void)n_in; (void)out_size; (void)ws_size;
  const float* enc   = (const float*)d_in[0];
  const float* q1    = (const float*)d_in[1];
  const float* qlast = (const float*)d_in[2];
  const float* mask  = (const float*)d_in[3];
  const float* Wqf   = (const float*)d_in[4];
  const float* Wql   = (const float*)d_in[5];
  const float* Wk    = (const float*)d_in[6];
  const float* Wv    = (const float*)d_in[7];
  const float* Wc    = (const float*)d_in[8];
  const float* bc    = (const float*)d_in[9];
  float* out = (float*)d_out;

  char* ws = (char*)d_ws;
  f16* Xnh  = (f16*)(ws + 0);           // 12864*512*2   = 13,172,736
  f16* Qcat = (f16*)(ws + 13172736);    // 12800*1024*2  = 26,214,400
  f16* WkvT = (f16*)(ws + 39387136);    // 1024*512*2    =  1,048,576
  f16* WqT  = (f16*)(ws + 40435712);    // 512*1024*2    =  1,048,576
  f16* WcT  = (f16*)(ws + 41484288);    // 512*512*2     =    524,288
  f16* Kp   = (f16*)(ws + 42008576);    // 12864*512*2   = 13,172,736
  f16* VT   = (f16*)(ws + 55181312);    // 64*16*32*208*2= 13,631,488
  f16* Qp   = (f16*)(ws + 68812800);    // 12800*512*2   = 13,107,200
  f16* Oc   = (f16*)(ws + 81920000);    // 12800*512*2   = 13,107,200
  f16* mhb  = (f16*)(ws + 95027200);    // 12800*512*2   = 13,107,200  (end 108,134,400)

  hipLaunchKernelGGL(prep_kernel, dim3(24352), dim3(256), 0, stream,
                     enc, q1, qlast, Wk, Wv, Wqf, Wql, Wc, Xnh, Qcat, WkvT, WqT, WcT);
  hipLaunchKernelGGL(gemm_proj, dim3(1208), dim3(256), 0, stream,
                     Xnh, WkvT, Kp, VT, Qcat, WqT, Qp);
  hipLaunchKernelGGL(attn_kernel, dim3(3328), dim3(256), 0, stream, Qp, Kp, VT, mask, Oc);
  hipLaunchKernelGGL(gemm_wc, dim3(400), dim3(256), 0, stream, Oc, WcT, mhb, bc);
  hipLaunchKernelGGL(final_kernel, dim3(832), dim3(256), 0, stream, mhb, Xnh, mask, out);
}